// Round 9
// baseline (685.543 us; speedup 1.0000x reference)
//
#include <hip/hip_runtime.h>
#include <hip/hip_fp16.h>

#define B_ 16
#define M_ 1024
#define N_ 4096
#define H_ 128
#define CIN_ 67

typedef _Float16 half8 __attribute__((ext_vector_type(8)));
typedef _Float16 half4_t __attribute__((ext_vector_type(4)));
typedef float f32x4 __attribute__((ext_vector_type(4)));
typedef short s16x4 __attribute__((ext_vector_type(4)));
typedef short s16x8 __attribute__((ext_vector_type(8)));

// ---------------------------------------------------------------------------
// P0: q = BN(cent @ Wq^T) * log2(e)  [log2-domain logits], k = BN(feat @ Wk^T).
// ---------------------------------------------------------------------------
#define SPA 104  // 96 + 8 pad, in halfs (row stride)

__global__ __launch_bounds__(256) void k_embed(
    const float* __restrict__ cent, const float* __restrict__ feat,
    const float* __restrict__ Wq, const float* __restrict__ Wk,
    const float* __restrict__ gq, const float* __restrict__ bq,
    const float* __restrict__ mq, const float* __restrict__ vq,
    const float* __restrict__ gk, const float* __restrict__ bk,
    const float* __restrict__ mk, const float* __restrict__ vk,
    __half* __restrict__ q16, __half* __restrict__ k16)
{
  __shared__ __align__(16) __half al[128 * SPA];
  __shared__ __align__(16) __half wl[128 * SPA];
  __shared__ float scl[128], shl[128];

  const int tid = threadIdx.x;
  const int wg  = blockIdx.x;
  const bool isq = (wg < 128);
  const int row0 = isq ? wg * 128 : (wg - 128) * 128;
  const float* in = isq ? cent : feat;
  const float* W  = isq ? Wq : Wk;
  const float* g  = isq ? gq : gk;
  const float* bb = isq ? bq : bk;
  const float* mm = isq ? mq : mk;
  const float* vv = isq ? vq : vk;
  __half* outp = isq ? q16 : k16;

  for (int i = tid; i < 128 * 29; i += 256) {
    int r = i / 29, c = 67 + (i - r * 29);
    al[r * SPA + c] = __float2half(0.f);
    wl[r * SPA + c] = __float2half(0.f);
  }
  for (int i = tid; i < 128 * CIN_; i += 256) {
    int r = i / CIN_, c = i - r * CIN_;
    al[r * SPA + c] = __float2half(in[(size_t)row0 * CIN_ + i]);
    wl[r * SPA + c] = __float2half(W[i]);
  }
  if (tid < 128) {
    float s = g[tid] * rsqrtf(vv[tid] + 1e-5f);
    float sc = isq ? 1.44269504088896f : 1.f;  // fold log2(e) into q
    scl[tid] = s * sc;
    shl[tid] = (bb[tid] - mm[tid] * s) * sc;
  }
  __syncthreads();

  const int lane = tid & 63, wv = tid >> 6;
  const int col = lane & 15, quad = lane >> 4;

  f32x4 acc[2][8];
#pragma unroll
  for (int ms = 0; ms < 2; ++ms)
#pragma unroll
    for (int ns = 0; ns < 8; ++ns) acc[ms][ns] = (f32x4){0.f, 0.f, 0.f, 0.f};

#pragma unroll
  for (int kk = 0; kk < 3; ++kk) {
    half8 af[2], bf[8];
#pragma unroll
    for (int ms = 0; ms < 2; ++ms)
      af[ms] = *(const half8*)&al[(wv * 32 + ms * 16 + col) * SPA + kk * 32 + quad * 8];
#pragma unroll
    for (int ns = 0; ns < 8; ++ns)
      bf[ns] = *(const half8*)&wl[(ns * 16 + col) * SPA + kk * 32 + quad * 8];
#pragma unroll
    for (int ms = 0; ms < 2; ++ms)
#pragma unroll
      for (int ns = 0; ns < 8; ++ns)
        acc[ms][ns] = __builtin_amdgcn_mfma_f32_16x16x32_f16(af[ms], bf[ns], acc[ms][ns], 0, 0, 0);
  }

#pragma unroll
  for (int ms = 0; ms < 2; ++ms)
#pragma unroll
    for (int reg = 0; reg < 4; ++reg) {
      int r = wv * 32 + ms * 16 + quad * 4 + reg;
#pragma unroll
      for (int ns = 0; ns < 8; ++ns) {
        int h = ns * 16 + col;
        float v = acc[ms][ns][reg] * scl[h] + shl[h];
        outp[(size_t)(row0 + r) * H_ + h] = __float2half(v);
      }
    }
}

// ---------------------------------------------------------------------------
// P1: SINGLE logits GEMM. x = q.k (log2 domain) quantized to int16 (x*256,
// resolution 1/256 -> rel err on p <= ln2/512 ~ 0.14%), transposed through
// LDS for coalesced stores. Z = sum 2^xq accumulated FROM THE QUANTIZED
// values during the store pass (exactly consistent with k_t's exp input).
// Replaces both the old attn1 and attn3's GEMM: the GEMM runs ONCE.
// ---------------------------------------------------------------------------
#define SPB 136  // 128 + 8 pad, in halfs/shorts

__global__ __launch_bounds__(256, 4) void k_logits(
    const __half* __restrict__ q16, const __half* __restrict__ k16,
    short* __restrict__ x16, float* __restrict__ Z)
{
  __shared__ __align__(16) __half qa[128 * SPB];  // 34,816 B; reused for xq

  const int tid = threadIdx.x;
  const int b = blockIdx.z, mt = blockIdx.y, nt = blockIdx.x;
  const int m0 = mt * 128, n0 = nt * 128;
  const int lane = tid & 63, wv = tid >> 6;
  const int col = lane & 15, quad = lane >> 4;

  // stage q-tile (shared operand)
  {
    uint4 qr[8];
    const uint4* sq = (const uint4*)(q16 + ((size_t)(b * M_) + m0) * H_);
#pragma unroll
    for (int j = 0; j < 8; ++j) qr[j] = sq[tid + 256 * j];
#pragma unroll
    for (int j = 0; j < 8; ++j) {
      int i = tid + 256 * j;
      *(uint4*)&qa[(i >> 4) * SPB + (i & 15) * 8] = qr[j];
    }
  }
  // per-wave k fragments (A operand: rows = n-local)
  half8 kf[4][2];
  {
    const __half* kb = k16 + ((size_t)(b * N_) + n0 + wv * 32 + col) * H_;
#pragma unroll
    for (int kk = 0; kk < 4; ++kk)
#pragma unroll
      for (int ms = 0; ms < 2; ++ms)
        kf[kk][ms] = *(const half8*)(kb + (size_t)ms * 16 * H_ + kk * 32 + quad * 8);
  }
  __syncthreads();

  // GEMM: acc[msN][nsm] — rows (quad*4+reg) = n-local, cols (col) = m-local
  f32x4 acc[2][8];
#pragma unroll
  for (int ms = 0; ms < 2; ++ms)
#pragma unroll
    for (int nb = 0; nb < 8; ++nb) acc[ms][nb] = (f32x4){0.f, 0.f, 0.f, 0.f};

#pragma unroll
  for (int kk = 0; kk < 4; ++kk) {
#pragma unroll
    for (int nb = 0; nb < 8; ++nb) {
      half8 bf = *(const half8*)&qa[(nb * 16 + col) * SPB + kk * 32 + quad * 8];
      acc[0][nb] = __builtin_amdgcn_mfma_f32_16x16x32_f16(kf[kk][0], bf, acc[0][nb], 0, 0, 0);
      acc[1][nb] = __builtin_amdgcn_mfma_f32_16x16x32_f16(kf[kk][1], bf, acc[1][nb], 0, 0, 0);
    }
  }
  __syncthreads();  // qa reads complete — buffer reused as int16 x-tile

  // quantize + transposed LDS write (rows = m-local)
  short* qs = (short*)qa;
#pragma unroll
  for (int msN = 0; msN < 2; ++msN) {
    const int nl = wv * 32 + msN * 16 + quad * 4;
#pragma unroll
    for (int nsm = 0; nsm < 8; ++nsm) {
      const int ml = nsm * 16 + col;
      s16x4 s4;
#pragma unroll
      for (int reg = 0; reg < 4; ++reg) {
        float x = fminf(fmaxf(acc[msN][nsm][reg], -126.f), 126.f);
        s4[reg] = (short)__float2int_rn(x * 256.f);
      }
      *(s16x4*)&qs[ml * SPB + nl] = s4;
    }
  }
  __syncthreads();

  // coalesced x16 store + Z partials from the QUANTIZED values
#pragma unroll
  for (int j = 0; j < 8; ++j) {
    int i = tid + 256 * j;
    int r = i >> 4, u = i & 15;
    s16x8 v = *(const s16x8*)&qs[r * SPB + u * 8];
    *(s16x8*)&x16[((size_t)(b * M_) + m0 + r) * N_ + n0 + u * 8] = v;
    float s = 0.f;
#pragma unroll
    for (int c = 0; c < 8; ++c) s += exp2f((float)v[c] * 0.00390625f);
    // lanes tid&15 = chunk u all share row r: reduce over u
    s += __shfl_xor(s, 1);
    s += __shfl_xor(s, 2);
    s += __shfl_xor(s, 4);
    s += __shfl_xor(s, 8);
    if ((tid & 15) == 0) atomicAdd(&Z[(size_t)b * M_ + m0 + r], s);
  }
}

// ---------------------------------------------------------------------------
// P2: pure streamer. t = sqrt((mask+1e-9)(2^(xq-lz)+1e-9))-1e-9 -> t16;
// colsum accumulated in registers (wg owns n-block exclusively per m-split),
// 128 atomics per wg. No MFMA, no big LDS -> max occupancy, deep MLP.
// grid (N/128, M/256, B) = (32, 4, 16).
// ---------------------------------------------------------------------------
__global__ __launch_bounds__(256, 6) void k_t(
    const short* __restrict__ x16, const float* __restrict__ mask,
    const float* __restrict__ Z, __half* __restrict__ t16,
    float* __restrict__ colsum)
{
  __shared__ float lzb[256];
  __shared__ float cb[4][128];

  const int tid = threadIdx.x;
  const int b = blockIdx.z, msp = blockIdx.y, nt = blockIdx.x;
  const int m1 = msp * 256, n0 = nt * 128;

  lzb[tid] = __log2f(Z[(size_t)b * M_ + m1 + tid]);
  __syncthreads();

  const int nlane = tid & 31, msub = tid >> 5;
  const int n = n0 + nlane * 4;

  float ca[4] = {0.f, 0.f, 0.f, 0.f};

  for (int mo = 0; mo < 32; mo += 4) {
    float4 mv[4];
    s16x4 xv[4];
    size_t bs[4];
#pragma unroll
    for (int k = 0; k < 4; ++k) {
      const int m = m1 + (mo + k) * 8 + msub;
      bs[k] = ((size_t)b * M_ + m) * N_ + n;
      mv[k] = *(const float4*)&mask[bs[k]];
      xv[k] = *(const s16x4*)&x16[bs[k]];
    }
#pragma unroll
    for (int k = 0; k < 4; ++k) {
      const float lz = lzb[(mo + k) * 8 + msub];
      half4_t h;
#pragma unroll
      for (int c = 0; c < 4; ++c) {
        float mvv = (c == 0) ? mv[k].x : (c == 1) ? mv[k].y : (c == 2) ? mv[k].z : mv[k].w;
        float p = (mvv < 1e-9f) ? 0.f : exp2f((float)xv[k][c] * 0.00390625f - lz);
        float t = sqrtf((mvv + 1e-9f) * (p + 1e-9f)) - 1e-9f;
        h[c] = (_Float16)t;
        ca[c] += t;
      }
      *(half4_t*)&t16[bs[k]] = h;
    }
  }

  // reduce colsum partials: msub pairs within wave, then across 4 waves
#pragma unroll
  for (int c = 0; c < 4; ++c) ca[c] += __shfl_xor(ca[c], 32);
  const int wv = tid >> 6;
  if ((tid & 63) < 32) {
#pragma unroll
    for (int c = 0; c < 4; ++c) cb[wv][nlane * 4 + c] = ca[c];
  }
  __syncthreads();
  if (tid < 128) {
    float s = cb[0][tid] + cb[1][tid] + cb[2][tid] + cb[3][tid];
    atomicAdd(&colsum[(size_t)b * N_ + n0 + tid], s);
  }
}

// ---------------------------------------------------------------------------
// P3: invert colsum in place.
// ---------------------------------------------------------------------------
__global__ __launch_bounds__(256) void k_icol(float* __restrict__ cs)
{
  int i = blockIdx.x * 256 + threadIdx.x;
  cs[i] = 1.f / fmaxf(cs[i], 1e-12f);
}

// ---------------------------------------------------------------------------
// P4: u = t * icolsum; out = u / max(rowsum(u),1e-12).
// ---------------------------------------------------------------------------
__global__ __launch_bounds__(256) void k_norm(
    const __half* __restrict__ t16, float* __restrict__ out,
    const float* __restrict__ icol)
{
  const int row = blockIdx.x;
  const int b = row >> 10;
  const half4_t* t4 = (const half4_t*)(t16 + (size_t)row * N_);
  float4* o4 = (float4*)(out + (size_t)row * N_);
  const float4* c4 = (const float4*)(icol + (size_t)b * N_);
  const int tid = threadIdx.x;

  float4 u[4];
  float s = 0.f;
#pragma unroll
  for (int j = 0; j < 4; ++j) {
    int idx = tid + 256 * j;
    half4_t h = t4[idx];
    float4 c = c4[idx];
    u[j].x = (float)h[0] * c.x;
    u[j].y = (float)h[1] * c.y;
    u[j].z = (float)h[2] * c.z;
    u[j].w = (float)h[3] * c.w;
    s += u[j].x + u[j].y + u[j].z + u[j].w;  // t >= 0 so |u| = u
  }
  s += __shfl_xor(s, 1);
  s += __shfl_xor(s, 2);
  s += __shfl_xor(s, 4);
  s += __shfl_xor(s, 8);
  s += __shfl_xor(s, 16);
  s += __shfl_xor(s, 32);
  __shared__ float red[4];
  if ((tid & 63) == 0) red[tid >> 6] = s;
  __syncthreads();
  float tot = red[0] + red[1] + red[2] + red[3];
  float inv = 1.f / fmaxf(tot, 1e-12f);
#pragma unroll
  for (int j = 0; j < 4; ++j) {
    int idx = tid + 256 * j;
    float4 v = u[j];
    v.x *= inv; v.y *= inv; v.z *= inv; v.w *= inv;
    o4[idx] = v;
  }
}

// ---------------------------------------------------------------------------
extern "C" void kernel_launch(void* const* d_in, const int* in_sizes, int n_in,
                              void* d_out, int out_size, void* d_ws, size_t ws_size,
                              hipStream_t stream) {
  const float* cent = (const float*)d_in[0];
  const float* feat = (const float*)d_in[1];
  const float* mask = (const float*)d_in[2];
  const float* Wq = (const float*)d_in[3];
  const float* Wk = (const float*)d_in[4];
  const float* gq = (const float*)d_in[5];
  const float* bq = (const float*)d_in[6];
  const float* mq = (const float*)d_in[7];
  const float* vq = (const float*)d_in[8];
  const float* gk = (const float*)d_in[9];
  const float* bk = (const float*)d_in[10];
  const float* mk = (const float*)d_in[11];
  const float* vk = (const float*)d_in[12];
  float* out = (float*)d_out;

  char* ws = (char*)d_ws;
  // workspace layout (bytes); total ~290 MB
  __half* q16  = (__half*)(ws + 0);            //   4,194,304
  __half* k16  = (__half*)(ws + 4194304);      //  16,777,216
  short* x16   = (short*)(ws + 20971520);      // 134,217,728
  __half* t16  = (__half*)(ws + 155189248);    // 134,217,728
  float* colsum= (float*)(ws + 289406976);     //     262,144
  float* Zr    = (float*)(ws + 289669120);     //      65,536

  // colsum + Z contiguous: one memset clears both
  hipMemsetAsync(colsum, 0, 262144 + 65536, stream);

  k_embed<<<640, 256, 0, stream>>>(cent, feat, Wq, Wk, gq, bq, mq, vq,
                                   gk, bk, mk, vk, q16, k16);

  dim3 gl(N_ / 128, M_ / 128, B_);  // (32, 8, 16) = 4096 wgs
  k_logits<<<gl, 256, 0, stream>>>(q16, k16, x16, Zr);

  dim3 gt(N_ / 128, M_ / 256, B_);  // (32, 4, 16) = 2048 wgs
  k_t<<<gt, 256, 0, stream>>>(x16, mask, Zr, t16, colsum);

  k_icol<<<B_ * N_ / 256, 256, 0, stream>>>(colsum);
  k_norm<<<B_ * M_, 256, 0, stream>>>(t16, out, colsum);
}